// Round 15
// baseline (163.473 us; speedup 1.0000x reference)
//
#include <hip/hip_runtime.h>
#include <hip/hip_bf16.h>

typedef __bf16 bf16x8_t __attribute__((ext_vector_type(8)));
typedef float f32x4_t __attribute__((ext_vector_type(4)));

#define SCALE_ZB 7.2134752044448169f   // 5 * log2(e): logits in log2 domain
#define LN2 0.69314718055994531f
#define E2(x) __builtin_amdgcn_exp2f(x)
#define LG2(x) __builtin_amdgcn_logf(x)
#define DEFER_THR 44.0f

// ws byte offsets
#define WS_CNT    256u       // int[2048]
#define WS_BASE   8448u      // int[2048]
#define WS_CUR    16640u     // int[2048]
#define WS_PERM   24832u     // int[65536]
#define WS_ANC    294912u    // bf16[262144] (512 KB), B-fragment order
#define WS_PART   819200u    // float2[65536*4] = 2 MB
#define WS_WSUM   2916352u   // float4[8192] (hp,pos,zsq,0 per hK wave)
#define WS_LSE    3047424u   // float[256]
#define WS_CPART  3048448u   // float[2048]
#define WS_ZERO   8448u      // zero cnt region only

// ---- anchors f32 -> bf16 packed in MFMA B-fragment order + label histogram ----
// layout: [chunk c 0..127][kk 0..3][lane 0..63][e 0..7]
__global__ void prepHist(const float* __restrict__ anc, __bf16* __restrict__ out,
                         const int* __restrict__ labels, int* __restrict__ cnt) {
    int i = blockIdx.x * 256 + threadIdx.x;   // 0..65535
    atomicAdd(&cnt[labels[i]], 1);
    if (i < 32768) {
        int m = i >> 4, k0 = (i & 15) << 3;
        int kk = k0 >> 5, g = (k0 >> 3) & 3, l15 = m & 15, c = m >> 4;
        int lane = (g << 4) | l15;
        int base = (((c << 2) + kk) << 9) + (lane << 3);
        const float4* a4 = (const float4*)anc + (size_t)m * 32 + (k0 >> 2);
        float4 f0 = a4[0], f1 = a4[1];
        bf16x8_t pk;
        pk[0] = (__bf16)f0.x; pk[1] = (__bf16)f0.y; pk[2] = (__bf16)f0.z; pk[3] = (__bf16)f0.w;
        pk[4] = (__bf16)f1.x; pk[5] = (__bf16)f1.y; pk[6] = (__bf16)f1.z; pk[7] = (__bf16)f1.w;
        *(bf16x8_t*)&out[base] = pk;
    }
}

__global__ void scanK(const int* __restrict__ cnt, int* __restrict__ base,
                      int* __restrict__ cursor) {
    __shared__ int wsum[4];
    int t = threadIdx.x, lane = t & 63, w = t >> 6;
    int c[8], tot = 0;
    #pragma unroll
    for (int q = 0; q < 8; ++q) { c[q] = cnt[t * 8 + q]; tot += c[q]; }
    int sc = tot;
    #pragma unroll
    for (int off = 1; off < 64; off <<= 1) {
        int o = __shfl_up(sc, off);
        if (lane >= off) sc += o;
    }
    if (lane == 63) wsum[w] = sc;
    __syncthreads();
    int woff = 0;
    for (int ww = 0; ww < w; ++ww) woff += wsum[ww];
    int ex = woff + sc - tot;
    #pragma unroll
    for (int q = 0; q < 8; ++q) {
        base[t * 8 + q] = ex;
        cursor[t * 8 + q] = ex;
        ex += c[q];
    }
}

__global__ void scatK(const int* __restrict__ labels, int* __restrict__ cursor,
                      int* __restrict__ perm) {
    int i = blockIdx.x * 256 + threadIdx.x;
    int l = labels[i];
    int p = atomicAdd(&cursor[l], 1);
    perm[p] = i;
}

// ---- GEMM+LSE: 1024 blocks x 4 waves; block = (b4, quarter q); wave w = row-group.
// All 4 waves share quarter q -> B-stream L1 reuse; staggered chunk start;
// per-row defer-max LSE (exact: lse = m + log2(sum 2^(v-m)) for any m).
__launch_bounds__(256)
__global__ void gemmK2(const float* __restrict__ z,
                       const __bf16* __restrict__ ancb,
                       float2* __restrict__ part) {
    const int tid  = threadIdx.x;
    const int lane = tid & 63;
    const int w    = tid >> 6;
    const int l15  = lane & 15, g = lane >> 4;
    const int q    = blockIdx.x & 3;
    const int b4   = blockIdx.x >> 2;       // 0..255
    const int rg   = (b4 << 2) + w;         // 0..1023
    const int R0   = rg << 6;               // 64 rows per wave
    const int c0   = (b4 * 7 + q * 11) & 31;

    // ---- A-fragments: 4 row-frags x 4 kk ----
    bf16x8_t Af[4][4];
    #pragma unroll
    for (int rf = 0; rf < 4; ++rf) {
        int row = R0 + (rf << 4) + l15;
        const float4* zr = (const float4*)z + ((size_t)row << 5);
        #pragma unroll
        for (int kk = 0; kk < 4; ++kk) {
            int qq = (kk << 3) + (g << 1);
            float4 z0 = zr[qq], z1 = zr[qq + 1];
            bf16x8_t pk;
            pk[0] = (__bf16)(z0.x * SCALE_ZB); pk[1] = (__bf16)(z0.y * SCALE_ZB);
            pk[2] = (__bf16)(z0.z * SCALE_ZB); pk[3] = (__bf16)(z0.w * SCALE_ZB);
            pk[4] = (__bf16)(z1.x * SCALE_ZB); pk[5] = (__bf16)(z1.y * SCALE_ZB);
            pk[6] = (__bf16)(z1.z * SCALE_ZB); pk[7] = (__bf16)(z1.w * SCALE_ZB);
            Af[rf][kk] = pk;
        }
    }

    float ms[4][4], ss[4][4];
    #pragma unroll
    for (int f = 0; f < 4; ++f)
        #pragma unroll
        for (int r = 0; r < 4; ++r) { ms[f][r] = -1.0e30f; ss[f][r] = 0.f; }

    const bf16x8_t* Bp = (const bf16x8_t*)ancb + (q << 13);

#define LOADB(Bx, ii) { int CC = (c0 + (ii)) & 31; _Pragma("unroll") \
    for (int kk = 0; kk < 4; ++kk) Bx[kk] = Bp[(((CC << 2) | kk) << 6) + lane]; }

#define CHUNK2D(Bx, By) { \
    f32x4_t a0[4], a1[4]; \
    _Pragma("unroll") \
    for (int f = 0; f < 4; ++f) { a0[f] = (f32x4_t){0.f,0.f,0.f,0.f}; a1[f] = (f32x4_t){0.f,0.f,0.f,0.f}; } \
    _Pragma("unroll") \
    for (int kk = 0; kk < 4; ++kk) \
        _Pragma("unroll") \
        for (int f = 0; f < 4; ++f) \
            a0[f] = __builtin_amdgcn_mfma_f32_16x16x32_bf16(Af[f][kk], Bx[kk], a0[f], 0, 0, 0); \
    _Pragma("unroll") \
    for (int kk = 0; kk < 4; ++kk) \
        _Pragma("unroll") \
        for (int f = 0; f < 4; ++f) \
            a1[f] = __builtin_amdgcn_mfma_f32_16x16x32_bf16(Af[f][kk], By[kk], a1[f], 0, 0, 0); \
    float bm = -1.0e30f; \
    _Pragma("unroll") \
    for (int f = 0; f < 4; ++f) \
        _Pragma("unroll") \
        for (int r = 0; r < 4; ++r) \
            bm = fmaxf(bm, fmaxf(a0[f][r], a1[f][r]) - ms[f][r]); \
    if (__any(bm > DEFER_THR)) { \
        _Pragma("unroll") \
        for (int f = 0; f < 4; ++f) \
            _Pragma("unroll") \
            for (int r = 0; r < 4; ++r) { \
                float v0 = a0[f][r], v1 = a1[f][r]; \
                float nm = fmaxf(fmaxf(v0, v1), ms[f][r]); \
                ss[f][r] = ss[f][r] * E2(ms[f][r] - nm) + E2(v0 - nm) + E2(v1 - nm); \
                ms[f][r] = nm; \
            } \
    } else { \
        _Pragma("unroll") \
        for (int f = 0; f < 4; ++f) \
            _Pragma("unroll") \
            for (int r = 0; r < 4; ++r) \
                ss[f][r] += E2(a0[f][r] - ms[f][r]) + E2(a1[f][r] - ms[f][r]); \
    } }

    bf16x8_t Ba[4], Bb[4], Bc[4], Bd[4];
    LOADB(Ba, 0) LOADB(Bb, 1) LOADB(Bc, 2) LOADB(Bd, 3)

    for (int c = 0; c < 32; c += 4) {
        CHUNK2D(Ba, Bb)
        if (c < 28) { LOADB(Ba, c + 4) LOADB(Bb, c + 5) }
        CHUNK2D(Bc, Bd)
        if (c < 28) { LOADB(Bc, c + 6) LOADB(Bd, c + 7) }
    }
#undef LOADB
#undef CHUNK2D

    // ---- merge (m,s) across the 16 anchor-lanes; write quarter partials ----
    #pragma unroll
    for (int f = 0; f < 4; ++f)
        #pragma unroll
        for (int r = 0; r < 4; ++r) {
            float m = ms[f][r], s = ss[f][r];
            #pragma unroll
            for (int off = 1; off < 16; off <<= 1) {
                float om = __shfl_xor(m, off), os = __shfl_xor(s, off);
                float nm = fmaxf(m, om);
                s = s * E2(m - nm) + os * E2(om - nm);
                m = nm;
            }
            ms[f][r] = m; ss[f][r] = s;
        }
    if (l15 == 0) {
        #pragma unroll
        for (int f = 0; f < 4; ++f)
            #pragma unroll
            for (int r = 0; r < 4; ++r) {
                int row0 = R0 + (f << 4) + (g << 2) + r;
                part[(row0 << 2) + q] = make_float2(ms[f][r], ss[f][r]);
            }
    }
}

// ---- h-align + pos-dot + zsq: 2048 blocks x 256 thr ----
__launch_bounds__(256)
__global__ void hK(const float* __restrict__ z,
                   const float* __restrict__ he,
                   const float* __restrict__ hc,
                   const float* __restrict__ ancf,
                   const int* __restrict__ labels,
                   float4* __restrict__ wsum) {
    const int tid = threadIdx.x, lane = tid & 63, w = tid >> 6;
    const int bid = blockIdx.x;

    float hp = 0.f;
    {
        int gt = (bid << 8) + tid;
        const float4* hev = (const float4*)he;
        const float4* hcv = (const float4*)hc;
        #pragma unroll 4
        for (int i = 0; i < 8; ++i) {
            float4 e = hev[(size_t)i * 524288 + gt];
            float4 c = hcv[(size_t)i * 524288 + gt];
            float dx = e.x - c.x, dy = e.y - c.y, dz = e.z - c.z, dw = e.w - c.w;
            hp += dx * dx + dy * dy + dz * dz + dw * dw;
        }
    }

    float pos = 0.f, zsq = 0.f;
    const int R = bid << 5;   // 32 rows per block
    #pragma unroll
    for (int i = 0; i < 4; ++i) {
        int idx = (i << 8) + tid;          // 0..1023 float4 slots (32 rows x 32)
        int r = idx >> 5, c4 = idx & 31;
        int row = R + r;
        int lb = labels[row];
        float4 zv = ((const float4*)z)[((size_t)row << 5) + c4];
        float4 av = ((const float4*)ancf)[((size_t)lb << 5) + c4];
        pos += zv.x*av.x + zv.y*av.y + zv.z*av.z + zv.w*av.w;
        zsq += zv.x*zv.x + zv.y*zv.y + zv.z*zv.z + zv.w*zv.w;
    }

    #pragma unroll
    for (int off = 32; off; off >>= 1) {
        hp  += __shfl_xor(hp, off);
        pos += __shfl_xor(pos, off);
        zsq += __shfl_xor(zsq, off);
    }
    if (lane == 0) wsum[(bid << 2) | w] = make_float4(hp, pos, zsq, 0.f);
}

// ---- centroid: 2048 blocks x 1 wave, one label each ----
__launch_bounds__(64)
__global__ void centK(const float* __restrict__ z,
                      const int* __restrict__ cnt,
                      const int* __restrict__ basep,
                      const int* __restrict__ perm,
                      float* __restrict__ cpart) {
    const int lane = threadIdx.x;
    const int lb = blockIdx.x;
    const int n = cnt[lb], bs = basep[lb];
    float ax = 0.f, ay = 0.f;
    const float2* z2 = (const float2*)z;
    for (int e0 = 0; e0 < n; e0 += 64) {
        int pe = (e0 + lane < n) ? perm[bs + e0 + lane] : 0;
        int c2 = n - e0; if (c2 > 64) c2 = 64;
        int j = 0;
        for (; j + 3 < c2; j += 4) {
            int r0 = __shfl(pe, j), r1 = __shfl(pe, j + 1);
            int r2 = __shfl(pe, j + 2), r3 = __shfl(pe, j + 3);
            float2 v0 = z2[((size_t)r0 << 6) + lane];
            float2 v1 = z2[((size_t)r1 << 6) + lane];
            float2 v2 = z2[((size_t)r2 << 6) + lane];
            float2 v3 = z2[((size_t)r3 << 6) + lane];
            ax += v0.x + v1.x + v2.x + v3.x;
            ay += v0.y + v1.y + v2.y + v3.y;
        }
        for (; j < c2; ++j) {
            int r0 = __shfl(pe, j);
            float2 v0 = z2[((size_t)r0 << 6) + lane];
            ax += v0.x; ay += v0.y;
        }
    }
    float ssq = ax * ax + ay * ay;
    #pragma unroll
    for (int off = 32; off; off >>= 1) ssq += __shfl_xor(ssq, off);
    if (lane == 0) cpart[lb] = ssq / fmaxf((float)n, 1.f);
}

// ---- merge the four M-quarter partials per row -> per-block lse partial ----
__global__ void mergeL(const float4* __restrict__ part4, float* __restrict__ lsePart) {
    __shared__ float wpart[4];
    int t = blockIdx.x * 256 + threadIdx.x;   // 0..65535 rows
    float4 A = part4[t << 1], Bq = part4[(t << 1) + 1];
    float nm = fmaxf(fmaxf(A.x, A.z), fmaxf(Bq.x, Bq.z));
    float s = A.y * E2(A.x - nm) + A.w * E2(A.z - nm)
            + Bq.y * E2(Bq.x - nm) + Bq.w * E2(Bq.z - nm);
    float lse = nm + LG2(s);
    #pragma unroll
    for (int off = 32; off; off >>= 1) lse += __shfl_xor(lse, off);
    if ((threadIdx.x & 63) == 0) wpart[threadIdx.x >> 6] = lse;
    __syncthreads();
    if (threadIdx.x == 0)
        lsePart[blockIdx.x] = wpart[0] + wpart[1] + wpart[2] + wpart[3];
}

// ---- final reduction ----
__global__ void finalR(const float4* __restrict__ wsum,
                       const float* __restrict__ lsePart,
                       const float* __restrict__ cpart,
                       float* __restrict__ out) {
    __shared__ float red[5][4];
    int t = threadIdx.x, lane = t & 63, w = t >> 6;
    float hp = 0.f, pos = 0.f, zsq = 0.f, cent = 0.f, lse = 0.f;
    #pragma unroll
    for (int i = 0; i < 32; ++i) {
        float4 v = wsum[i * 256 + t];
        hp += v.x; pos += v.y; zsq += v.z;
    }
    #pragma unroll
    for (int i = 0; i < 8; ++i) cent += cpart[i * 256 + t];
    lse = lsePart[t];
    #pragma unroll
    for (int off = 32; off; off >>= 1) {
        hp  += __shfl_xor(hp, off);
        pos += __shfl_xor(pos, off);
        zsq += __shfl_xor(zsq, off);
        cent += __shfl_xor(cent, off);
        lse += __shfl_xor(lse, off);
    }
    if (lane == 0) {
        red[0][w] = hp; red[1][w] = pos; red[2][w] = zsq; red[3][w] = cent; red[4][w] = lse;
    }
    __syncthreads();
    if (t == 0) {
        float H = red[0][0] + red[0][1] + red[0][2] + red[0][3];
        float P = red[1][0] + red[1][1] + red[1][2] + red[1][3];
        float Z = red[2][0] + red[2][1] + red[2][2] + red[2][3];
        float C = red[3][0] + red[3][1] + red[3][2] + red[3][3];
        float L = red[4][0] + red[4][1] + red[4][2] + red[4][3];
        float lc    = (LN2 * L - 5.0f * P) * (1.0f / 65536.0f);
        float cent2 = (Z - C) * (1.0f / 8388608.0f);
        float hal   = H * (1.0f / 16777216.0f);
        out[0] = lc + 0.05f * cent2 + 0.1f * hal;
    }
}

extern "C" void kernel_launch(void* const* d_in, const int* in_sizes, int n_in,
                              void* d_out, int out_size, void* d_ws, size_t ws_size,
                              hipStream_t stream) {
    const float* z      = (const float*)d_in[0];
    const float* he     = (const float*)d_in[1];
    const float* hc     = (const float*)d_in[2];
    const float* anc    = (const float*)d_in[3];
    const int*   labels = (const int*)d_in[4];

    char* ws = (char*)d_ws;
    int*    cnt     = (int*)(ws + WS_CNT);
    int*    basep   = (int*)(ws + WS_BASE);
    int*    cursor  = (int*)(ws + WS_CUR);
    int*    perm    = (int*)(ws + WS_PERM);
    __bf16* ancb    = (__bf16*)(ws + WS_ANC);
    float2* part    = (float2*)(ws + WS_PART);
    float4* wsum    = (float4*)(ws + WS_WSUM);
    float*  lsePart = (float*)(ws + WS_LSE);
    float*  cpart   = (float*)(ws + WS_CPART);

    hipMemsetAsync(d_ws, 0, WS_ZERO, stream);
    prepHist<<<256, 256, 0, stream>>>(anc, ancb, labels, cnt);
    scanK<<<1, 256, 0, stream>>>(cnt, basep, cursor);
    scatK<<<256, 256, 0, stream>>>(labels, cursor, perm);
    gemmK2<<<1024, 256, 0, stream>>>(z, ancb, part);
    hK<<<2048, 256, 0, stream>>>(z, he, hc, anc, labels, wsum);
    centK<<<2048, 64, 0, stream>>>(z, cnt, basep, perm, cpart);
    mergeL<<<256, 256, 0, stream>>>((const float4*)part, lsePart);
    finalR<<<1, 256, 0, stream>>>(wsum, lsePart, cpart, (float*)d_out);
}

// Round 16
// 116.116 us; speedup vs baseline: 1.4078x; 1.4078x over previous
//
#include <hip/hip_runtime.h>
#include <hip/hip_bf16.h>

typedef __bf16 bf16x8_t __attribute__((ext_vector_type(8)));
typedef float f32x4_t __attribute__((ext_vector_type(4)));

#define SCALE_ZB 7.2134752044448169f   // 5 * log2(e): logits in log2 domain
#define LN2 0.69314718055994531f
#define E2(x) __builtin_amdgcn_exp2f(x)
#define LG2(x) __builtin_amdgcn_logf(x)

// ws byte offsets
#define WS_CNT    256u       // int[2048]
#define WS_BASE   8448u      // int[2048]
#define WS_CUR    16640u     // int[2048]
#define WS_PERM   24832u     // int[65536]
#define WS_ANC    294912u    // bf16[262144] (512 KB), B-fragment order
#define WS_PART   819200u    // float2[65536*4] = 2 MB
#define WS_WSUM   2916352u   // float4[4096] (hp,pos,zsq,0 per H block)
#define WS_LSE    2981888u   // float[256]
#define WS_CPART  2982912u   // float[2048]
#define WS_ZERO   8448u      // zero cnt region only

// ---- anchors f32 -> bf16 packed in MFMA B-fragment order + label histogram ----
// layout: [chunk c 0..127][kk 0..3][lane 0..63][e 0..7]
__global__ void prepHist(const float* __restrict__ anc, __bf16* __restrict__ out,
                         const int* __restrict__ labels, int* __restrict__ cnt) {
    int i = blockIdx.x * 256 + threadIdx.x;   // 0..65535
    atomicAdd(&cnt[labels[i]], 1);
    if (i < 32768) {
        int m = i >> 4, k0 = (i & 15) << 3;
        int kk = k0 >> 5, g = (k0 >> 3) & 3, l15 = m & 15, c = m >> 4;
        int lane = (g << 4) | l15;
        int base = (((c << 2) + kk) << 9) + (lane << 3);
        const float4* a4 = (const float4*)anc + (size_t)m * 32 + (k0 >> 2);
        float4 f0 = a4[0], f1 = a4[1];
        bf16x8_t pk;
        pk[0] = (__bf16)f0.x; pk[1] = (__bf16)f0.y; pk[2] = (__bf16)f0.z; pk[3] = (__bf16)f0.w;
        pk[4] = (__bf16)f1.x; pk[5] = (__bf16)f1.y; pk[6] = (__bf16)f1.z; pk[7] = (__bf16)f1.w;
        *(bf16x8_t*)&out[base] = pk;
    }
}

__global__ void scanK(const int* __restrict__ cnt, int* __restrict__ base,
                      int* __restrict__ cursor) {
    __shared__ int wsum[4];
    int t = threadIdx.x, lane = t & 63, w = t >> 6;
    int c[8], tot = 0;
    #pragma unroll
    for (int q = 0; q < 8; ++q) { c[q] = cnt[t * 8 + q]; tot += c[q]; }
    int sc = tot;
    #pragma unroll
    for (int off = 1; off < 64; off <<= 1) {
        int o = __shfl_up(sc, off);
        if (lane >= off) sc += o;
    }
    if (lane == 63) wsum[w] = sc;
    __syncthreads();
    int woff = 0;
    for (int ww = 0; ww < w; ++ww) woff += wsum[ww];
    int ex = woff + sc - tot;
    #pragma unroll
    for (int q = 0; q < 8; ++q) {
        base[t * 8 + q] = ex;
        cursor[t * 8 + q] = ex;
        ex += c[q];
    }
}

__global__ void scatK(const int* __restrict__ labels, int* __restrict__ cursor,
                      int* __restrict__ perm) {
    int i = blockIdx.x * 256 + threadIdx.x;
    int l = labels[i];
    int p = atomicAdd(&cursor[l], 1);
    perm[p] = i;
}

// Heterogeneous 10240 x 64-thr blocks, role = bid % 5:
//   0,1 -> GEMM (4096 blocks): R11 gemmK structure verbatim; quarter = gi>>10
//          so co-resident blocks share quarter + chunk order (L1 B reuse).
//   2,3 -> H (4096 blocks): h-align slice + pos/zsq over 16 z-rows.
//   4   -> cent (2048 blocks): one label each (R11 centK).
// Zero global atomics; slot stores only.
__launch_bounds__(64, 2)
__global__ void mega64(const float* __restrict__ z,
                       const float* __restrict__ he,
                       const float* __restrict__ hc,
                       const float* __restrict__ ancf,
                       const int* __restrict__ labels,
                       const __bf16* __restrict__ ancb,
                       const int* __restrict__ cnt,
                       const int* __restrict__ basep,
                       const int* __restrict__ perm,
                       float4* __restrict__ wsum,
                       float* __restrict__ cpart,
                       float2* __restrict__ part) {
    const int lane = threadIdx.x;
    const int bid  = blockIdx.x;
    const int role = bid % 5;
    const int b5   = bid / 5;

    if (role < 2) {
        // ================= GEMM role (R11 gemmK verbatim) =================
        const int gi  = (b5 << 1) + role;   // 0..4095
        const int q   = gi >> 10;           // quarter: phase-major -> L2/L1 shared
        const int rg  = gi & 1023;          // row-group
        const int R0  = rg << 6;            // 64 rows per wave
        const int l15 = lane & 15, g = lane >> 4;

        bf16x8_t Af[4][4];
        #pragma unroll
        for (int rf = 0; rf < 4; ++rf) {
            int row = R0 + (rf << 4) + l15;
            const float4* zr = (const float4*)z + ((size_t)row << 5);
            #pragma unroll
            for (int kk = 0; kk < 4; ++kk) {
                int qq = (kk << 3) + (g << 1);
                float4 z0 = zr[qq], z1 = zr[qq + 1];
                bf16x8_t pk;
                pk[0] = (__bf16)(z0.x * SCALE_ZB); pk[1] = (__bf16)(z0.y * SCALE_ZB);
                pk[2] = (__bf16)(z0.z * SCALE_ZB); pk[3] = (__bf16)(z0.w * SCALE_ZB);
                pk[4] = (__bf16)(z1.x * SCALE_ZB); pk[5] = (__bf16)(z1.y * SCALE_ZB);
                pk[6] = (__bf16)(z1.z * SCALE_ZB); pk[7] = (__bf16)(z1.w * SCALE_ZB);
                Af[rf][kk] = pk;
            }
        }

        float ms[4][4], ss[4][4];
        #pragma unroll
        for (int f = 0; f < 4; ++f)
            #pragma unroll
            for (int r = 0; r < 4; ++r) { ms[f][r] = -1.0e30f; ss[f][r] = 0.f; }

        const bf16x8_t* Bp = (const bf16x8_t*)ancb + (q << 13);

#define LOADB(Bx, cc) { _Pragma("unroll") \
        for (int kk = 0; kk < 4; ++kk) Bx[kk] = Bp[((((cc) << 2) | kk) << 6) + lane]; }

#define CHUNK2(Bx, By) { \
        f32x4_t a0[4], a1[4]; \
        _Pragma("unroll") \
        for (int f = 0; f < 4; ++f) { a0[f] = (f32x4_t){0.f,0.f,0.f,0.f}; a1[f] = (f32x4_t){0.f,0.f,0.f,0.f}; } \
        _Pragma("unroll") \
        for (int kk = 0; kk < 4; ++kk) \
            _Pragma("unroll") \
            for (int f = 0; f < 4; ++f) \
                a0[f] = __builtin_amdgcn_mfma_f32_16x16x32_bf16(Af[f][kk], Bx[kk], a0[f], 0, 0, 0); \
        _Pragma("unroll") \
        for (int kk = 0; kk < 4; ++kk) \
            _Pragma("unroll") \
            for (int f = 0; f < 4; ++f) \
                a1[f] = __builtin_amdgcn_mfma_f32_16x16x32_bf16(Af[f][kk], By[kk], a1[f], 0, 0, 0); \
        _Pragma("unroll") \
        for (int f = 0; f < 4; ++f) \
            _Pragma("unroll") \
            for (int r = 0; r < 4; ++r) { \
                float v0 = a0[f][r], v1 = a1[f][r]; \
                float nm = fmaxf(fmaxf(v0, v1), ms[f][r]); \
                ss[f][r] = ss[f][r] * E2(ms[f][r] - nm) + E2(v0 - nm) + E2(v1 - nm); \
                ms[f][r] = nm; \
            } }

        bf16x8_t Ba[4], Bb[4], Bc[4], Bd[4];
        LOADB(Ba, 0) LOADB(Bb, 1) LOADB(Bc, 2) LOADB(Bd, 3)

        for (int c = 0; c < 32; c += 4) {
            CHUNK2(Ba, Bb)
            if (c < 28) { LOADB(Ba, c + 4) LOADB(Bb, c + 5) }
            CHUNK2(Bc, Bd)
            if (c < 28) { LOADB(Bc, c + 6) LOADB(Bd, c + 7) }
        }
#undef LOADB
#undef CHUNK2

        #pragma unroll
        for (int f = 0; f < 4; ++f)
            #pragma unroll
            for (int r = 0; r < 4; ++r) {
                float m = ms[f][r], s = ss[f][r];
                #pragma unroll
                for (int off = 1; off < 16; off <<= 1) {
                    float om = __shfl_xor(m, off), os = __shfl_xor(s, off);
                    float nm = fmaxf(m, om);
                    s = s * E2(m - nm) + os * E2(om - nm);
                    m = nm;
                }
                ms[f][r] = m; ss[f][r] = s;
            }
        if (l15 == 0) {
            #pragma unroll
            for (int f = 0; f < 4; ++f)
                #pragma unroll
                for (int r = 0; r < 4; ++r) {
                    int row0 = R0 + (f << 4) + (g << 2) + r;
                    part[(row0 << 2) + q] = make_float2(ms[f][r], ss[f][r]);
                }
        }

    } else if (role < 4) {
        // ================= H role: h-align + pos/zsq (16 rows) =================
        const int hi = (b5 << 1) + (role - 2);   // 0..4095

        float hp = 0.f;
        {
            int gt = (hi << 6) + lane;            // 0..262143
            const float4* hev = (const float4*)he;
            const float4* hcv = (const float4*)hc;
            #pragma unroll 4
            for (int i = 0; i < 16; ++i) {
                float4 e = hev[(size_t)i * 262144 + gt];
                float4 c = hcv[(size_t)i * 262144 + gt];
                float dx = e.x - c.x, dy = e.y - c.y, dz = e.z - c.z, dw = e.w - c.w;
                hp += dx * dx + dy * dy + dz * dz + dw * dw;
            }
        }

        float pos = 0.f, zsq = 0.f;
        const int R = hi << 4;   // 16 rows per block
        #pragma unroll
        for (int i = 0; i < 8; ++i) {
            int idx = (i << 6) + lane;            // 0..511 float4 slots (16x32)
            int r = idx >> 5, c4 = idx & 31;
            int row = R + r;
            int lb = labels[row];
            float4 zv = ((const float4*)z)[((size_t)row << 5) + c4];
            float4 av = ((const float4*)ancf)[((size_t)lb << 5) + c4];
            pos += zv.x*av.x + zv.y*av.y + zv.z*av.z + zv.w*av.w;
            zsq += zv.x*zv.x + zv.y*zv.y + zv.z*zv.z + zv.w*zv.w;
        }

        #pragma unroll
        for (int off = 32; off; off >>= 1) {
            hp  += __shfl_xor(hp, off);
            pos += __shfl_xor(pos, off);
            zsq += __shfl_xor(zsq, off);
        }
        if (lane == 0) wsum[hi] = make_float4(hp, pos, zsq, 0.f);

    } else {
        // ================= cent role: one label =================
        const int lb = b5;                        // 0..2047
        const int n = cnt[lb], bs = basep[lb];
        float ax = 0.f, ay = 0.f;
        const float2* z2 = (const float2*)z;
        for (int e0 = 0; e0 < n; e0 += 64) {
            int pe = (e0 + lane < n) ? perm[bs + e0 + lane] : 0;
            int c2 = n - e0; if (c2 > 64) c2 = 64;
            int j = 0;
            for (; j + 3 < c2; j += 4) {
                int r0 = __shfl(pe, j), r1 = __shfl(pe, j + 1);
                int r2 = __shfl(pe, j + 2), r3 = __shfl(pe, j + 3);
                float2 v0 = z2[((size_t)r0 << 6) + lane];
                float2 v1 = z2[((size_t)r1 << 6) + lane];
                float2 v2 = z2[((size_t)r2 << 6) + lane];
                float2 v3 = z2[((size_t)r3 << 6) + lane];
                ax += v0.x + v1.x + v2.x + v3.x;
                ay += v0.y + v1.y + v2.y + v3.y;
            }
            for (; j < c2; ++j) {
                int r0 = __shfl(pe, j);
                float2 v0 = z2[((size_t)r0 << 6) + lane];
                ax += v0.x; ay += v0.y;
            }
        }
        float ssq = ax * ax + ay * ay;
        #pragma unroll
        for (int off = 32; off; off >>= 1) ssq += __shfl_xor(ssq, off);
        if (lane == 0) cpart[lb] = ssq / fmaxf((float)n, 1.f);
    }
}

// ---- merge the four M-quarter partials per row -> per-block lse partial ----
__global__ void mergeL(const float4* __restrict__ part4, float* __restrict__ lsePart) {
    __shared__ float wpart[4];
    int t = blockIdx.x * 256 + threadIdx.x;   // 0..65535 rows
    float4 A = part4[t << 1], Bq = part4[(t << 1) + 1];
    float nm = fmaxf(fmaxf(A.x, A.z), fmaxf(Bq.x, Bq.z));
    float s = A.y * E2(A.x - nm) + A.w * E2(A.z - nm)
            + Bq.y * E2(Bq.x - nm) + Bq.w * E2(Bq.z - nm);
    float lse = nm + LG2(s);
    #pragma unroll
    for (int off = 32; off; off >>= 1) lse += __shfl_xor(lse, off);
    if ((threadIdx.x & 63) == 0) wpart[threadIdx.x >> 6] = lse;
    __syncthreads();
    if (threadIdx.x == 0)
        lsePart[blockIdx.x] = wpart[0] + wpart[1] + wpart[2] + wpart[3];
}

// ---- final reduction: 4096 H slots + 2048 cent partials + 256 lse partials ----
__global__ void finalR(const float4* __restrict__ wsum,
                       const float* __restrict__ lsePart,
                       const float* __restrict__ cpart,
                       float* __restrict__ out) {
    __shared__ float red[5][4];
    int t = threadIdx.x, lane = t & 63, w = t >> 6;
    float hp = 0.f, pos = 0.f, zsq = 0.f, cent = 0.f, lse = 0.f;
    #pragma unroll
    for (int i = 0; i < 16; ++i) {
        float4 v = wsum[i * 256 + t];
        hp += v.x; pos += v.y; zsq += v.z;
    }
    #pragma unroll
    for (int i = 0; i < 8; ++i) cent += cpart[i * 256 + t];
    lse = lsePart[t];
    #pragma unroll
    for (int off = 32; off; off >>= 1) {
        hp  += __shfl_xor(hp, off);
        pos += __shfl_xor(pos, off);
        zsq += __shfl_xor(zsq, off);
        cent += __shfl_xor(cent, off);
        lse += __shfl_xor(lse, off);
    }
    if (lane == 0) {
        red[0][w] = hp; red[1][w] = pos; red[2][w] = zsq; red[3][w] = cent; red[4][w] = lse;
    }
    __syncthreads();
    if (t == 0) {
        float H = red[0][0] + red[0][1] + red[0][2] + red[0][3];
        float P = red[1][0] + red[1][1] + red[1][2] + red[1][3];
        float Z = red[2][0] + red[2][1] + red[2][2] + red[2][3];
        float C = red[3][0] + red[3][1] + red[3][2] + red[3][3];
        float L = red[4][0] + red[4][1] + red[4][2] + red[4][3];
        float lc    = (LN2 * L - 5.0f * P) * (1.0f / 65536.0f);
        float cent2 = (Z - C) * (1.0f / 8388608.0f);
        float hal   = H * (1.0f / 16777216.0f);
        out[0] = lc + 0.05f * cent2 + 0.1f * hal;
    }
}

extern "C" void kernel_launch(void* const* d_in, const int* in_sizes, int n_in,
                              void* d_out, int out_size, void* d_ws, size_t ws_size,
                              hipStream_t stream) {
    const float* z      = (const float*)d_in[0];
    const float* he     = (const float*)d_in[1];
    const float* hc     = (const float*)d_in[2];
    const float* anc    = (const float*)d_in[3];
    const int*   labels = (const int*)d_in[4];

    char* ws = (char*)d_ws;
    int*    cnt     = (int*)(ws + WS_CNT);
    int*    basep   = (int*)(ws + WS_BASE);
    int*    cursor  = (int*)(ws + WS_CUR);
    int*    perm    = (int*)(ws + WS_PERM);
    __bf16* ancb    = (__bf16*)(ws + WS_ANC);
    float2* part    = (float2*)(ws + WS_PART);
    float4* wsum    = (float4*)(ws + WS_WSUM);
    float*  lsePart = (float*)(ws + WS_LSE);
    float*  cpart   = (float*)(ws + WS_CPART);

    hipMemsetAsync(d_ws, 0, WS_ZERO, stream);
    prepHist<<<256, 256, 0, stream>>>(anc, ancb, labels, cnt);
    scanK<<<1, 256, 0, stream>>>(cnt, basep, cursor);
    scatK<<<256, 256, 0, stream>>>(labels, cursor, perm);
    mega64<<<10240, 64, 0, stream>>>(z, he, hc, anc, labels, ancb, cnt, basep, perm,
                                     wsum, cpart, part);
    mergeL<<<256, 256, 0, stream>>>((const float4*)part, lsePart);
    finalR<<<1, 256, 0, stream>>>(wsum, lsePart, cpart, (float*)d_out);
}